// Round 2
// baseline (718.888 us; speedup 1.0000x reference)
//
#include <hip/hip_runtime.h>
#include <cstdint>
#include <cstddef>

#define B_DIM 4
#define C_DIM 512
#define T_DIM 1024
#define D_DIM 128
#define L_DIM 101
#define O_DIM 128

// ---------------- K0: transpose W_proj (128x512) -> WpT (512x128) ----------------
__global__ __launch_bounds__(256) void wpt_kernel(const float* __restrict__ Wp,
                                                  float* __restrict__ WpT) {
    const int idx = blockIdx.x * 256 + threadIdx.x;   // 65536 total
    const int c = idx >> 7;
    const int d = idx & 127;
    WpT[idx] = Wp[d * C_DIM + c];   // write coalesced, read scattered (L2)
}

// ---------------- K1a: spatial mean pool, contiguity-blocked ----------------
// Block = (b, 16 c's, 128 t's) -> per-c run is 128*256B = 32 KB CONTIGUOUS
// (old kernel: 1 KB runs at 256 KB power-of-2 stride -> DRAM-unfriendly).
// 1024 blocks, 4/CU.  Writes feat[b][t][c] (8 MB ws).
#define PC 16
#define PT 128
__global__ __launch_bounds__(256) void pool_kernel(const float* __restrict__ x,
                                                   float* __restrict__ feat) {
    __shared__ float fs[PC][PT + 1];   // +1: write-out column reads conflict-free
    const int tid = threadIdx.x;
    const int bid = blockIdx.x;        // b*256 + cc*8 + tt
    const int b   = bid >> 8;
    const int cc  = (bid >> 3) & 31;
    const int tt  = bid & 7;
    const int c0  = cc * PC;
    const int t0  = tt * PT;

    // 512 KB per block: 32 iters, each thread owns one 64 B chunk (= 1/4 of a
    // (c,t) cell), 4 independent float4 loads, 2-step width-4 xor reduce.
    #pragma unroll 4
    for (int it = 0; it < 32; ++it) {
        const int g  = it * 256 + tid;   // 64B-chunk id within block
        const int cl = g >> 9;           // 512 chunks per 32 KB c-run
        const int wi = g & 511;
        const float* src = x + ((size_t)(b * C_DIM + c0 + cl) * T_DIM + t0) * 64
                             + (size_t)wi * 16;
        const float4 v0 = *(const float4*)(src + 0);
        const float4 v1 = *(const float4*)(src + 4);
        const float4 v2 = *(const float4*)(src + 8);
        const float4 v3 = *(const float4*)(src + 12);
        float s = (v0.x + v0.y + v0.z + v0.w) + (v1.x + v1.y + v1.z + v1.w)
                + (v2.x + v2.y + v2.z + v2.w) + (v3.x + v3.y + v3.z + v3.w);
        s += __shfl_xor(s, 1, 4);
        s += __shfl_xor(s, 2, 4);
        if ((tid & 3) == 0) fs[cl][wi >> 2] = s * (1.0f / 64.0f);
    }
    __syncthreads();

    // write feat[b][t][c]: 64 B granules (16 c's) at 2 KB stride
    #pragma unroll
    for (int j = 0; j < (PC * PT) / 256; ++j) {   // 8
        const int idx = j * 256 + tid;
        const int t   = idx >> 4;
        const int cl  = idx & 15;
        feat[((size_t)(b << 10) + t0 + t) * C_DIM + c0 + cl] = fs[cl][t];
    }
}

// ---------------- K1b: proj + L2-normalize (reads feat ws) ----------------
#define ROWS 4
__global__ __launch_bounds__(256) void proj_kernel(const float* __restrict__ feat,
                                                   const float* __restrict__ WpT,
                                                   float* __restrict__ p) {
    __shared__ __align__(16) float feat_s[ROWS * C_DIM];   // 8 KB [row][c]
    __shared__ float red_s[8 * ROWS * D_DIM];              // 16 KB [strm][row][d]
    __shared__ float nrm_s[ROWS * 2];
    const int tid = threadIdx.x;
    const int bt0 = blockIdx.x * ROWS;

    // ---- phase A: contiguous 8 KB copy (feat rows t0..t0+3) ----
    {
        const float4* src = (const float4*)(feat + (size_t)bt0 * C_DIM);
        float4* dst = (float4*)feat_s;
        dst[tid]       = src[tid];
        dst[256 + tid] = src[256 + tid];
    }
    __syncthreads();

    // ---- phase B: proj.  lane owns d-quad, strm owns c = 8k+strm ----
    {
        const int lane4 = (tid & 31) << 2;   // d0
        const int strm  = tid >> 5;          // 0..7
        float a0[4] = {0,0,0,0}, a1[4] = {0,0,0,0}, a2[4] = {0,0,0,0}, a3[4] = {0,0,0,0};
        for (int ci = 0; ci < C_DIM / 8; ++ci) {
            const int c = ci * 8 + strm;
            const float4 w = *(const float4*)(WpT + (size_t)c * D_DIM + lane4);
            const float f0 = feat_s[0 * C_DIM + c];
            const float f1 = feat_s[1 * C_DIM + c];
            const float f2 = feat_s[2 * C_DIM + c];
            const float f3 = feat_s[3 * C_DIM + c];
            a0[0] += f0 * w.x; a0[1] += f0 * w.y; a0[2] += f0 * w.z; a0[3] += f0 * w.w;
            a1[0] += f1 * w.x; a1[1] += f1 * w.y; a1[2] += f1 * w.z; a1[3] += f1 * w.w;
            a2[0] += f2 * w.x; a2[1] += f2 * w.y; a2[2] += f2 * w.z; a2[3] += f2 * w.w;
            a3[0] += f3 * w.x; a3[1] += f3 * w.y; a3[2] += f3 * w.z; a3[3] += f3 * w.w;
        }
        float* rb = red_s + strm * (ROWS * D_DIM) + lane4;
        *(float4*)(rb + 0 * D_DIM) = make_float4(a0[0], a0[1], a0[2], a0[3]);
        *(float4*)(rb + 1 * D_DIM) = make_float4(a1[0], a1[1], a1[2], a1[3]);
        *(float4*)(rb + 2 * D_DIM) = make_float4(a2[0], a2[1], a2[2], a2[3]);
        *(float4*)(rb + 3 * D_DIM) = make_float4(a3[0], a3[1], a3[2], a3[3]);
    }
    __syncthreads();

    // ---- phase C: combine streams + row-norm + store ----
    float pv[2];
    const int lane = tid & 63;
    const int wv   = tid >> 6;
    #pragma unroll
    for (int j = 0; j < 2; ++j) {
        const int idx = j * 256 + tid;       // row*128 + d
        float v = 0.f;
        #pragma unroll
        for (int s = 0; s < 8; ++s) v += red_s[s * (ROWS * D_DIM) + idx];
        pv[j] = v;
        float ss = v * v;
        ss += __shfl_xor(ss, 32, 64);
        ss += __shfl_xor(ss, 16, 64);
        ss += __shfl_xor(ss,  8, 64);
        ss += __shfl_xor(ss,  4, 64);
        ss += __shfl_xor(ss,  2, 64);
        ss += __shfl_xor(ss,  1, 64);
        if (lane == 0) {
            const int row  = (j * 4 + wv) >> 1;
            const int half = wv & 1;
            nrm_s[row * 2 + half] = ss;
        }
    }
    __syncthreads();
    #pragma unroll
    for (int j = 0; j < 2; ++j) {
        const int idx = j * 256 + tid;
        const int row = idx >> 7;
        const int d   = idx & 127;
        const float ss  = nrm_s[row * 2] + nrm_s[row * 2 + 1];
        const float inv = 1.0f / fmaxf(sqrtf(ss), 1e-12f);
        p[(size_t)(bt0 + row) * D_DIM + d] = pv[j] * inv;
    }
}

// ---------------- K2: fused banded similarity + FC + relu (UNCHANGED) ----------------
#define TT 8
#define PS 132
#define NR 109
#define FS 108
#define SMEM_F (TT * FS + O_DIM * FS)

__global__ __launch_bounds__(256) void band_fc_kernel(const float* __restrict__ p,
                                                      const float* __restrict__ Wfc,
                                                      const float* __restrict__ bfc,
                                                      float* __restrict__ out) {
    __shared__ float smem[SMEM_F];
    float* p_s = smem;                                  // [NR][PS]
    const int tid = threadIdx.x;
    const int b   = blockIdx.x >> 7;
    const int t0  = (blockIdx.x & 127) * TT;

    for (int idx = tid; idx < NR * (D_DIM / 4); idx += 256) {
        const int i  = idx >> 5;
        const int k4 = (idx & 31) << 2;
        const int r  = t0 - 50 + i;
        float4 v = make_float4(0.f, 0.f, 0.f, 0.f);
        if (r >= 0 && r < T_DIM)
            v = *(const float4*)(p + (size_t)((b << 10) + r) * D_DIM + k4);
        *(float4*)(p_s + i * PS + k4) = v;
    }
    __syncthreads();

    float c00 = 0.f, c01 = 0.f, c10 = 0.f, c11 = 0.f;
    const bool active = tid < 4 * 51;
    const int tp = active ? (tid / 51) : 0;
    const int lq = active ? (tid - tp * 51) : 0;
    {
        const float* pa0  = p_s + (2 * tp + 50) * PS;
        const float* pa1  = pa0 + PS;
        const float* pb00 = p_s + (2 * tp + lq) * PS;
        const float* pb01 = pb00 + PS;
        const float* pb10 = p_s + (2 * tp + lq + 51) * PS;
        const float* pb11 = pb10 + PS;
        #pragma unroll 4
        for (int k = 0; k < D_DIM; k += 4) {
            const float4 a0 = *(const float4*)(pa0 + k);
            const float4 a1 = *(const float4*)(pa1 + k);
            const float4 b0 = *(const float4*)(pb00 + k);
            const float4 b1 = *(const float4*)(pb01 + k);
            const float4 b2 = *(const float4*)(pb10 + k);
            const float4 b3 = *(const float4*)(pb11 + k);
            c00 += a0.x * b0.x + a0.y * b0.y + a0.z * b0.z + a0.w * b0.w;
            c01 += a1.x * b1.x + a1.y * b1.y + a1.z * b1.z + a1.w * b1.w;
            c10 += a0.x * b2.x + a0.y * b2.y + a0.z * b2.z + a0.w * b2.w;
            c11 += a1.x * b3.x + a1.y * b3.y + a1.z * b3.z + a1.w * b3.w;
        }
    }
    __syncthreads();

    float* band_s = smem;               // [TT][FS]
    float* wfc_s  = smem + TT * FS;     // [O_DIM][FS]
    if (active) {
        band_s[(2 * tp + 0) * FS + lq] = c00;
        band_s[(2 * tp + 1) * FS + lq] = c01;
        if (lq < 50) {
            band_s[(2 * tp + 0) * FS + lq + 51] = c10;
            band_s[(2 * tp + 1) * FS + lq + 51] = c11;
        }
    }
    for (int i = tid; i < TT * 7; i += 256) {
        const int t = i / 7;
        band_s[t * FS + L_DIM + (i - t * 7)] = 0.f;
    }
    for (int i = tid; i < O_DIM * L_DIM; i += 256) {
        const int o = i / L_DIM;
        wfc_s[o * FS + (i - o * L_DIM)] = Wfc[i];
    }
    for (int i = tid; i < O_DIM * 7; i += 256) {
        const int o = i / 7;
        wfc_s[o * FS + L_DIM + (i - o * 7)] = 0.f;
    }
    __syncthreads();

    const int o  = tid & 127;
    const int th = tid >> 7;
    const float bias = bfc[o];
    float acc0 = bias, acc1 = bias, acc2 = bias, acc3 = bias;
    const float* w  = wfc_s + o * FS;
    const float* bd = band_s + (th * 4) * FS;
    #pragma unroll 4
    for (int k = 0; k < 104; k += 4) {
        const float4 wv = *(const float4*)(w + k);
        const float4 b0 = *(const float4*)(bd + 0 * FS + k);
        const float4 b1 = *(const float4*)(bd + 1 * FS + k);
        const float4 b2 = *(const float4*)(bd + 2 * FS + k);
        const float4 b3 = *(const float4*)(bd + 3 * FS + k);
        acc0 += wv.x * b0.x + wv.y * b0.y + wv.z * b0.z + wv.w * b0.w;
        acc1 += wv.x * b1.x + wv.y * b1.y + wv.z * b1.z + wv.w * b1.w;
        acc2 += wv.x * b2.x + wv.y * b2.y + wv.z * b2.z + wv.w * b2.w;
        acc3 += wv.x * b3.x + wv.y * b3.y + wv.z * b3.z + wv.w * b3.w;
    }
    const size_t obase = (size_t)((b << 10) + t0 + th * 4) * O_DIM + o;
    out[obase + 0 * O_DIM] = fmaxf(acc0, 0.f);
    out[obase + 1 * O_DIM] = fmaxf(acc1, 0.f);
    out[obase + 2 * O_DIM] = fmaxf(acc2, 0.f);
    out[obase + 3 * O_DIM] = fmaxf(acc3, 0.f);
}

extern "C" void kernel_launch(void* const* d_in, const int* in_sizes, int n_in,
                              void* d_out, int out_size, void* d_ws, size_t ws_size,
                              hipStream_t stream) {
    const float* x   = (const float*)d_in[0];
    const float* Wp  = (const float*)d_in[1];
    const float* Wfc = (const float*)d_in[2];
    const float* bfc = (const float*)d_in[3];
    float* out = (float*)d_out;

    char* ws = (char*)d_ws;
    float* WpT  = (float*)(ws);                            // 256 KB
    float* p    = (float*)(ws + (size_t)1024 * 1024);      // 2 MB
    float* feat = (float*)(ws + (size_t)4 * 1024 * 1024);  // 8 MB

    wpt_kernel <<<(C_DIM * D_DIM) / 256, 256, 0, stream>>>(Wp, WpT);
    pool_kernel<<<B_DIM * 32 * 8, 256, 0, stream>>>(x, feat);
    proj_kernel<<<(B_DIM * T_DIM) / ROWS, 256, 0, stream>>>(feat, WpT, p);
    band_fc_kernel<<<B_DIM * (T_DIM / TT), 256, 0, stream>>>(p, Wfc, bfc, out);
}